// Round 7
// baseline (237.579 us; speedup 1.0000x reference)
//
#include <hip/hip_runtime.h>
#include <math.h>

// Outputs are a pure function of obs's class (NC=1000); heads (am/sd/cr)
// are a pure function of the VQ CODE (VQN=512). Structure as R9:
//   compute: blocks [0,nTB) trunk+VQ (2 classes, shared f4 loads);
//            blocks [nTB,+nHB) heads per code (2 codes/block).
//   scatter: out[b] = tables[idx_t[obs[b]]].
//
// R10: R9's batched loads didn't materialize — hipcc re-sinks each load
// to first use under pressure, recreating ~500cy/load serialization
// (model retro-dicts R7's 47us exactly). Fix: pin each load batch with
// __builtin_amdgcn_sched_barrier(0) (loads can't sink, FMAs can't hoist),
// and prefetch trunk layer L+1's weights before layer L's FMA phase so
// each phase's latency hides under the previous phase's compute+barriers.
// No arithmetic change: all chains/orders/tie-breaks == R9 => absmax 0.

typedef float f4 __attribute__((ext_vector_type(4)));
typedef float f2 __attribute__((ext_vector_type(2)));

#define SB0() __builtin_amdgcn_sched_barrier(0)

__device__ __forceinline__ float sigmoidf_(float x){ return 1.0f/(1.0f + expf(-x)); }

__global__ __launch_bounds__(256) void compute_kernel(
    const float* __restrict__ embed,
    const float* __restrict__ W1, const float* __restrict__ b1,
    const float* __restrict__ W2, const float* __restrict__ b2,
    const float* __restrict__ W3, const float* __restrict__ b3,
    const float* __restrict__ Wp, const float* __restrict__ bp,
    const float* __restrict__ cb,
    const float* __restrict__ Wa, const float* __restrict__ ba,
    const float* __restrict__ Ws, const float* __restrict__ bs,
    const float* __restrict__ Wc1, const float* __restrict__ bc1,
    const float* __restrict__ Wc2, const float* __restrict__ bc2,
    const float* __restrict__ Wc3, const float* __restrict__ bc3,
    const float* __restrict__ Wc4, const float* __restrict__ bc4,
    float* __restrict__ am_c, float* __restrict__ sd_c,
    float* __restrict__ cr_c, int* __restrict__ idx_t, float* __restrict__ e_t,
    float* __restrict__ loss_slot, int VQN, int NC, int nTB)
{
    const int bid = blockIdx.x;
    const int t   = threadIdx.x;     // 0..255
    if (bid == 0 && t == 0) *loss_slot = 0.0f;   // d_out is poisoned each call

    // trunk-branch LDS
    __shared__ double U[2][128], V[2][128];     // layer ping-pong (class A/B)
    __shared__ double part[2][8][128];          // fp64 chain partials
    __shared__ double zp2[2][64];
    __shared__ float  qv2[2][64];
    __shared__ double rda[2][4];
    __shared__ int    ria[2][4];
    __shared__ int    widx2[2];
    // head-branch LDS
    __shared__ float  qvh[2][64];
    __shared__ float  fpart[2][4][128];
    __shared__ float  gpart[2][2][128];
    __shared__ float  h1s[2][128], h2s[2][128], h3s[2][32];

    if (bid < nTB) {
        // ================= trunk + VQ for classes c0, c1 =================
        const int c0  = bid * 2;
        const int c1  = (c0 + 1 < NC) ? c0 + 1 : NC - 1;   // clamp (dup-safe)
        const int cls = t >> 7;          // this thread's class for combines
        const int r   = t & 127;
        const int q4  = (t & 31) << 2;   // output quad (shared-load phases)
        const int h   = t >> 5;          // K-chain 0..7 (i ≡ h mod 8)
        const int q4p = (r & 15) << 2;   // zp-phase mapping
        const int hp  = r >> 4;          // 0..7

        // FMA phase: consumes pre-loaded weight regs WR/bias BB; chain
        // order identical to R9. Followed by barrier+combine (caller).
#define TFMA(WR, BB, IN)                                                      \
        {                                                                     \
            double aA0 = (h == 0) ? (double)BB.x : 0.0;                       \
            double aA1 = (h == 0) ? (double)BB.y : 0.0;                       \
            double aA2 = (h == 0) ? (double)BB.z : 0.0;                       \
            double aA3 = (h == 0) ? (double)BB.w : 0.0;                       \
            double aB0 = aA0, aB1 = aA1, aB2 = aA2, aB3 = aA3;                \
            _Pragma("unroll")                                                 \
            for (int s = 0; s < 16; ++s) {                                    \
                int i = h + (s << 3);                                         \
                double w0 = (double)WR[s].x, w1 = (double)WR[s].y;            \
                double w2 = (double)WR[s].z, w3 = (double)WR[s].w;            \
                double xA = IN[0][i], xB = IN[1][i];                          \
                aA0 = fma(xA, w0, aA0);  aB0 = fma(xB, w0, aB0);              \
                aA1 = fma(xA, w1, aA1);  aB1 = fma(xB, w1, aB1);              \
                aA2 = fma(xA, w2, aA2);  aB2 = fma(xB, w2, aB2);              \
                aA3 = fma(xA, w3, aA3);  aB3 = fma(xB, w3, aB3);              \
            }                                                                 \
            part[0][h][q4+0] = aA0; part[0][h][q4+1] = aA1;                   \
            part[0][h][q4+2] = aA2; part[0][h][q4+3] = aA3;                   \
            part[1][h][q4+0] = aB0; part[1][h][q4+1] = aB1;                   \
            part[1][h][q4+2] = aB2; part[1][h][q4+3] = aB3;                   \
        }
#define COMBINE(OUT)                                                          \
        __syncthreads();                                                      \
        {                                                                     \
            double acc = ((part[cls][0][r] + part[cls][1][r])                 \
                        + (part[cls][2][r] + part[cls][3][r]))                \
                       + ((part[cls][4][r] + part[cls][5][r])                 \
                        + (part[cls][6][r] + part[cls][7][r]));               \
            OUT[cls][r] = acc > 0.0 ? acc : 0.0;                              \
        }                                                                     \
        __syncthreads();

        f4 wa[16], wb[16];

        // batch W1 + W2 before the embed barrier; pin with sched_barrier
        #pragma unroll
        for (int s = 0; s < 16; ++s)
            wa[s] = *(const f4*)(W1 + (size_t)(h + (s << 3)) * 128 + q4);
        f4 bb1 = *(const f4*)(b1 + q4);
        SB0();
        #pragma unroll
        for (int s = 0; s < 16; ++s)
            wb[s] = *(const f4*)(W2 + (size_t)(h + (s << 3)) * 128 + q4);
        f4 bb2 = *(const f4*)(b2 + q4);
        SB0();

        if (t < 128) U[0][t] = (double)embed[(size_t)c0 * 128 + t];
        else         U[1][r] = (double)embed[(size_t)c1 * 128 + r];
        __syncthreads();

        TFMA(wa, bb1, U)
        COMBINE(V)

        // prefetch W3 (reuse wa) while W2's FMA runs next
        #pragma unroll
        for (int s = 0; s < 16; ++s)
            wa[s] = *(const f4*)(W3 + (size_t)(h + (s << 3)) * 128 + q4);
        f4 bb3 = *(const f4*)(b3 + q4);
        SB0();

        TFMA(wb, bb2, V)
        COMBINE(U)

        // prefetch Wp (zp mapping, reuse wb) while W3's FMA runs next
        #pragma unroll
        for (int s = 0; s < 16; ++s)
            wb[s] = *(const f4*)(Wp + (size_t)(hp + (s << 3)) * 64 + q4p);
        f4 bbp = *(const f4*)(bp + q4p);
        SB0();

        TFMA(wa, bb3, U)
        COMBINE(V)
#undef TFMA
#undef COMBINE

        // zp = z3 @ Wp + bp (64 outs/class): 8 chains x 16 quads
        {
            double a0 = (hp == 0) ? (double)bbp.x : 0.0;
            double a1 = (hp == 0) ? (double)bbp.y : 0.0;
            double a2 = (hp == 0) ? (double)bbp.z : 0.0;
            double a3 = (hp == 0) ? (double)bbp.w : 0.0;
            #pragma unroll
            for (int s = 0; s < 16; ++s) {
                int i = hp + (s << 3);
                double x = V[cls][i];
                a0 = fma(x, (double)wb[s].x, a0);
                a1 = fma(x, (double)wb[s].y, a1);
                a2 = fma(x, (double)wb[s].z, a2);
                a3 = fma(x, (double)wb[s].w, a3);
            }
            part[cls][hp][q4p+0] = a0; part[cls][hp][q4p+1] = a1;
            part[cls][hp][q4p+2] = a2; part[cls][hp][q4p+3] = a3;
        }
        __syncthreads();
        if (r < 64) {
            zp2[cls][r] = ((part[cls][0][r] + part[cls][1][r])
                         + (part[cls][2][r] + part[cls][3][r]))
                        + ((part[cls][4][r] + part[cls][5][r])
                         + (part[cls][6][r] + part[cls][7][r]));
        }
        __syncthreads();

        // VQ argmin: thread t owns codes t, t+256; both codes' 16 row-f4s
        // batched+pinned, then distance chains (R9's exact order, k
        // ascending: t first, then t+256).
        double bestA = 1e300, bestB = 1e300; int biA = 0, biB = 0;
        if (VQN == 512) {
            f4 v0[16], v1[16];
            const float* crow0 = cb + (size_t)t * 64;
            const float* crow1 = cb + (size_t)(t + 256) * 64;
            #pragma unroll
            for (int j4 = 0; j4 < 16; ++j4) v0[j4] = *(const f4*)(crow0 + (j4 << 2));
            #pragma unroll
            for (int j4 = 0; j4 < 16; ++j4) v1[j4] = *(const f4*)(crow1 + (j4 << 2));
            SB0();
            #pragma unroll
            for (int kk2 = 0; kk2 < 2; ++kk2) {
                double sA0 = 0.0, sA1 = 0.0, sB0 = 0.0, sB1 = 0.0;
                #pragma unroll
                for (int j4 = 0; j4 < 16; ++j4) {
                    f4 v = kk2 ? v1[j4] : v0[j4];
                    int j = j4 << 2;
                    double w0 = (double)v.x, w1 = (double)v.y;
                    double w2 = (double)v.z, w3 = (double)v.w;
                    double dA0 = zp2[0][j+0] - w0, dA1 = zp2[0][j+1] - w1;
                    double dA2 = zp2[0][j+2] - w2, dA3 = zp2[0][j+3] - w3;
                    double dB0 = zp2[1][j+0] - w0, dB1 = zp2[1][j+1] - w1;
                    double dB2 = zp2[1][j+2] - w2, dB3 = zp2[1][j+3] - w3;
                    sA0 = fma(dA0, dA0, sA0);  sA1 = fma(dA1, dA1, sA1);
                    sA0 = fma(dA2, dA2, sA0);  sA1 = fma(dA3, dA3, sA1);
                    sB0 = fma(dB0, dB0, sB0);  sB1 = fma(dB1, dB1, sB1);
                    sB0 = fma(dB2, dB2, sB0);  sB1 = fma(dB3, dB3, sB1);
                }
                double sA = sA0 + sA1, sB = sB0 + sB1;
                int k = t + (kk2 << 8);
                if (sA < bestA) { bestA = sA; biA = k; }
                if (sB < bestB) { bestB = sB; biB = k; }
            }
        } else {
            for (int k = t; k < VQN; k += 256) {
                const float* crow = cb + (size_t)k * 64;
                f4 v[16];
                #pragma unroll
                for (int j4 = 0; j4 < 16; ++j4) v[j4] = *(const f4*)(crow + (j4 << 2));
                SB0();
                double sA0 = 0.0, sA1 = 0.0, sB0 = 0.0, sB1 = 0.0;
                #pragma unroll
                for (int j4 = 0; j4 < 16; ++j4) {
                    int j = j4 << 2;
                    double w0 = (double)v[j4].x, w1 = (double)v[j4].y;
                    double w2 = (double)v[j4].z, w3 = (double)v[j4].w;
                    double dA0 = zp2[0][j+0] - w0, dA1 = zp2[0][j+1] - w1;
                    double dA2 = zp2[0][j+2] - w2, dA3 = zp2[0][j+3] - w3;
                    double dB0 = zp2[1][j+0] - w0, dB1 = zp2[1][j+1] - w1;
                    double dB2 = zp2[1][j+2] - w2, dB3 = zp2[1][j+3] - w3;
                    sA0 = fma(dA0, dA0, sA0);  sA1 = fma(dA1, dA1, sA1);
                    sA0 = fma(dA2, dA2, sA0);  sA1 = fma(dA3, dA3, sA1);
                    sB0 = fma(dB0, dB0, sB0);  sB1 = fma(dB1, dB1, sB1);
                    sB0 = fma(dB2, dB2, sB0);  sB1 = fma(dB3, dB3, sB1);
                }
                double sA = sA0 + sA1, sB = sB0 + sB1;
                if (sA < bestA) { bestA = sA; biA = k; }
                if (sB < bestB) { bestB = sB; biB = k; }
            }
        }
        // (min d, min idx) lattice within wave, then across 4 waves via LDS
        for (int off = 32; off > 0; off >>= 1) {
            double od = __shfl_down(bestA, off);
            int    oi = __shfl_down(biA, off);
            if (od < bestA || (od == bestA && oi < biA)) { bestA = od; biA = oi; }
            od = __shfl_down(bestB, off);
            oi = __shfl_down(biB, off);
            if (od < bestB || (od == bestB && oi < biB)) { bestB = od; biB = oi; }
        }
        {
            int wv = t >> 6;
            if ((t & 63) == 0) {
                rda[0][wv] = bestA; ria[0][wv] = biA;
                rda[1][wv] = bestB; ria[1][wv] = biB;
            }
        }
        __syncthreads();
        if (t < 2) {
            double b0 = rda[t][0]; int i0 = ria[t][0];
            for (int wv = 1; wv < 4; ++wv) {
                if (rda[t][wv] < b0 || (rda[t][wv] == b0 && ria[t][wv] < i0)) {
                    b0 = rda[t][wv]; i0 = ria[t][wv];
                }
            }
            widx2[t] = i0;
        }
        __syncthreads();
        const int widxA = widx2[0], widxB = widx2[1];
        if (t < 64)       qv2[0][t]      = cb[(size_t)widxA * 64 + t];
        else if (t < 128) qv2[1][t - 64] = cb[(size_t)widxB * 64 + (t - 64)];
        __syncthreads();

        if (t == 0) {
            idx_t[c0] = widxA;
            double e0 = 0.0, e1 = 0.0;
            for (int j = 0; j < 64; j += 2) {
                double d0 = (double)qv2[0][j]   - zp2[0][j];
                double d1 = (double)qv2[0][j+1] - zp2[0][j+1];
                e0 = fma(d0, d0, e0); e1 = fma(d1, d1, e1);
            }
            e_t[c0] = (float)(e0 + e1);
        }
        if (t == 128 && c1 != c0) {
            idx_t[c1] = widxB;
            double e0 = 0.0, e1 = 0.0;
            for (int j = 0; j < 64; j += 2) {
                double d0 = (double)qv2[1][j]   - zp2[1][j];
                double d1 = (double)qv2[1][j+1] - zp2[1][j+1];
                e0 = fma(d0, d0, e0); e1 = fma(d1, d1, e1);
            }
            e_t[c1] = (float)(e0 + e1);
        }
    } else {
        // ============ heads per CODE (2 codes/block, pinned batches) ============
        const int g  = t >> 7;                 // code slot 0/1
        const int tt = t & 127;
        int k = (bid - nTB) * 2 + g;
        const int kk = (k < VQN) ? k : VQN - 1;    // clamp (dup-safe)
        const int q4 = (tt & 31) << 2;

        // H1 weight batch (32 f4) issued before the qvh barrier
        const int m  = tt >> 6;
        const int hh1 = (tt >> 5) & 1;
        const float* Wm = m ? Ws : Wa;
        const float* bm = m ? bs : ba;
        f4 hw[32];
        #pragma unroll
        for (int s = 0; s < 32; ++s)
            hw[s] = *(const f4*)(Wm + (size_t)(hh1 + (s << 1)) * 128 + q4);
        f4 bbh = *(const f4*)(bm + q4);
        SB0();

        if (tt < 64) qvh[g][tt] = cb[(size_t)kk * 64 + tt];
        __syncthreads();

        // H1: chain order == R9 (s = 0..31 sequential)
        {
            float a0 = hh1 ? 0.0f : bbh.x;
            float a1 = hh1 ? 0.0f : bbh.y;
            float a2 = hh1 ? 0.0f : bbh.z;
            float a3 = hh1 ? 0.0f : bbh.w;
            #pragma unroll
            for (int s = 0; s < 32; ++s) {
                float qj = qvh[g][hh1 + (s << 1)];
                a0 = fmaf(qj, hw[s].x, a0);
                a1 = fmaf(qj, hw[s].y, a1);
                a2 = fmaf(qj, hw[s].z, a2);
                a3 = fmaf(qj, hw[s].w, a3);
            }
            fpart[g][tt >> 5][q4+0] = a0; fpart[g][tt >> 5][q4+1] = a1;
            fpart[g][tt >> 5][q4+2] = a2; fpart[g][tt >> 5][q4+3] = a3;
        }
        __syncthreads();

        // H2: tt<64 compute Wc1 chains (pinned batch); tt>=64 store am/sd
        if (tt < 64) {
            const int hh = tt >> 5;
            #pragma unroll
            for (int s = 0; s < 32; ++s)
                hw[s] = *(const f4*)(Wc1 + (size_t)(hh + (s << 1)) * 128 + q4);
            f4 bb = *(const f4*)(bc1 + q4);
            SB0();
            float a0 = hh ? 0.0f : bb.x;
            float a1 = hh ? 0.0f : bb.y;
            float a2 = hh ? 0.0f : bb.z;
            float a3 = hh ? 0.0f : bb.w;
            #pragma unroll
            for (int s = 0; s < 32; ++s) {
                float qj = qvh[g][hh + (s << 1)];
                a0 = fmaf(qj, hw[s].x, a0);
                a1 = fmaf(qj, hw[s].y, a1);
                a2 = fmaf(qj, hw[s].z, a2);
                a3 = fmaf(qj, hw[s].w, a3);
            }
            gpart[g][hh][q4+0] = a0; gpart[g][hh][q4+1] = a1;
            gpart[g][hh][q4+2] = a2; gpart[g][hh][q4+3] = a3;
        } else {
            int o = (tt - 64) << 1;
            am_c[(size_t)kk * 128 + o]     = sigmoidf_(fpart[g][0][o]   + fpart[g][1][o]);
            am_c[(size_t)kk * 128 + o + 1] = sigmoidf_(fpart[g][0][o+1] + fpart[g][1][o+1]);
            sd_c[(size_t)kk * 128 + o]     = sigmoidf_(fpart[g][2][o]   + fpart[g][3][o])   * 1.0f + 1e-8f;
            sd_c[(size_t)kk * 128 + o + 1] = sigmoidf_(fpart[g][2][o+1] + fpart[g][3][o+1]) * 1.0f + 1e-8f;
        }
        __syncthreads();
        h1s[g][tt] = sigmoidf_(gpart[g][0][tt] + gpart[g][1][tt]);
        __syncthreads();

        // critic layer 2 (128->128): 64 f2 loads pinned as one batch;
        // FMA order s=0..63 sequential (== R9's 4x16 groups)
        {
            const int o2 = (tt & 63) << 1;
            const int hh = tt >> 6;
            f2 cw[64];
            #pragma unroll
            for (int s = 0; s < 64; ++s)
                cw[s] = *(const f2*)(Wc2 + (size_t)(hh + (s << 1)) * 128 + o2);
            f2 bb = *(const f2*)(bc2 + o2);
            SB0();
            float a0 = hh ? 0.0f : bb.x;
            float a1 = hh ? 0.0f : bb.y;
            #pragma unroll
            for (int s = 0; s < 64; ++s) {
                float x = h1s[g][hh + (s << 1)];
                a0 = fmaf(x, cw[s].x, a0);
                a1 = fmaf(x, cw[s].y, a1);
            }
            gpart[g][hh][o2+0] = a0; gpart[g][hh][o2+1] = a1;
        }
        __syncthreads();
        h2s[g][tt] = sigmoidf_(gpart[g][0][tt] + gpart[g][1][tt]);
        __syncthreads();

        // critic layer 3 (128->32): 64 f2 pinned batch, tt<32
        if (tt < 32) {
            const int o2 = (tt & 15) << 1;
            const int hh = tt >> 4;
            f2 cw[64];
            #pragma unroll
            for (int s = 0; s < 64; ++s)
                cw[s] = *(const f2*)(Wc3 + (size_t)(hh + (s << 1)) * 32 + o2);
            f2 bb = *(const f2*)(bc3 + o2);
            SB0();
            float a0 = hh ? 0.0f : bb.x;
            float a1 = hh ? 0.0f : bb.y;
            #pragma unroll
            for (int s = 0; s < 64; ++s) {
                float x = h2s[g][hh + (s << 1)];
                a0 = fmaf(x, cw[s].x, a0);
                a1 = fmaf(x, cw[s].y, a1);
            }
            gpart[g][hh][o2+0] = a0; gpart[g][hh][o2+1] = a1;
        }
        __syncthreads();
        if (tt < 32) h3s[g][tt] = sigmoidf_(gpart[g][0][tt] + gpart[g][1][tt]);
        __syncthreads();

        if (tt == 0) {
            f4 w4[8];
            #pragma unroll
            for (int s = 0; s < 8; ++s) w4[s] = *(const f4*)(Wc4 + (s << 2));
            SB0();
            float l4 = bc4[0];
            #pragma unroll
            for (int i = 0; i < 32; ++i) {
                float wv = (i & 3) == 0 ? w4[i >> 2].x :
                           (i & 3) == 1 ? w4[i >> 2].y :
                           (i & 3) == 2 ? w4[i >> 2].z : w4[i >> 2].w;
                l4 = fmaf(h3s[g][i], wv, l4);
            }
            cr_c[kk] = l4;             // no sigmoid on final critic layer
        }
    }
}

// Merged scatter: blocks [0, vecBlocks) emit BOTH am and sd float4 per
// thread from one obs read + one idx_t indirection (L1-hot, 4 KB);
// trailing blocks do the critic/idx scatter and vq_loss reduction.
__global__ __launch_bounds__(256) void scatter_kernel(
    const int* __restrict__ obs,
    const f4* __restrict__ am_c, const f4* __restrict__ sd_c,
    const float* __restrict__ cr_c, const int* __restrict__ idx_t,
    const float* __restrict__ e_t,
    f4* __restrict__ out_vec, float* __restrict__ out_critic,
    float* __restrict__ out_idx, float* __restrict__ out_loss,
    int B, float scale)
{
    __shared__ float red[256];
    const int vecBlocks = (B * 32) / 256;           // B*128/4 f4-slots per half
    if ((int)blockIdx.x < vecBlocks) {
        int gid = blockIdx.x * 256 + threadIdx.x;
        int b = gid >> 5;                           // 32 float4 per row
        int j = gid & 31;
        int k = idx_t[obs[b]];
        size_t row = (size_t)k * 32 + j;
        __builtin_nontemporal_store(am_c[row], &out_vec[gid]);
        __builtin_nontemporal_store(sd_c[row], &out_vec[(size_t)B * 32 + gid]);
        return;
    }
    int b = (blockIdx.x - vecBlocks) * 256 + threadIdx.x;
    float e = 0.0f;
    if (b < B) {
        int o = obs[b];
        int k = idx_t[o];
        __builtin_nontemporal_store(cr_c[k], &out_critic[b]);
        __builtin_nontemporal_store((float)k, &out_idx[b]);
        e = e_t[o];
    }
    red[threadIdx.x] = e;
    __syncthreads();
    for (int s = 128; s > 0; s >>= 1) {
        if (threadIdx.x < s) red[threadIdx.x] += red[threadIdx.x + s];
        __syncthreads();
    }
    if (threadIdx.x == 0) atomicAdd(out_loss, red[0] * scale);
}

extern "C" void kernel_launch(void* const* d_in, const int* in_sizes, int n_in,
                              void* d_out, int out_size, void* d_ws, size_t ws_size,
                              hipStream_t stream)
{
    const int*   obs   = (const int*)  d_in[0];
    const float* embed = (const float*)d_in[1];
    const float* W1    = (const float*)d_in[2];
    const float* b1    = (const float*)d_in[3];
    const float* W2    = (const float*)d_in[4];
    const float* b2    = (const float*)d_in[5];
    const float* W3    = (const float*)d_in[6];
    const float* b3    = (const float*)d_in[7];
    const float* Wp    = (const float*)d_in[8];
    const float* bp    = (const float*)d_in[9];
    const float* cb    = (const float*)d_in[10];
    const float* Wa    = (const float*)d_in[11];
    const float* ba    = (const float*)d_in[12];
    const float* Ws    = (const float*)d_in[13];
    const float* bs    = (const float*)d_in[14];
    const float* Wc1   = (const float*)d_in[15];
    const float* bc1   = (const float*)d_in[16];
    const float* Wc2   = (const float*)d_in[17];
    const float* bc2   = (const float*)d_in[18];
    const float* Wc3   = (const float*)d_in[19];
    const float* bc3   = (const float*)d_in[20];
    const float* Wc4   = (const float*)d_in[21];
    const float* bc4   = (const float*)d_in[22];

    const int B   = in_sizes[0];
    const int NC  = in_sizes[1] / 128;
    const int VQN = in_sizes[10] / 64;

    // workspace tables: per-code am/sd/cr + per-class idx/e (~530 KB)
    float* am_c = (float*)d_ws;
    float* sd_c = am_c + (size_t)VQN * 128;
    float* cr_c = sd_c + (size_t)VQN * 128;
    float* e_t  = cr_c + VQN;
    int*   idx_t = (int*)(e_t + NC);

    float* out = (float*)d_out;
    const size_t cr_off   = (size_t)B * 256;     // after am (B*128) + sd (B*128)
    const size_t loss_off = cr_off + (size_t)B;
    const size_t idx_off  = loss_off + 1;

    const int nTB = (NC + 1) / 2;                // trunk blocks (2 classes each)
    const int nHB = (VQN + 1) / 2;               // head blocks (2 codes each)

    compute_kernel<<<nTB + nHB, 256, 0, stream>>>(
        embed, W1, b1, W2, b2, W3, b3, Wp, bp, cb,
        Wa, ba, Ws, bs, Wc1, bc1, Wc2, bc2, Wc3, bc3, Wc4, bc4,
        am_c, sd_c, cr_c, idx_t, e_t, out + loss_off, VQN, NC, nTB);

    const int vecBlocks    = (B * 32) / 256;
    const int scalarBlocks = (B + 255) / 256;
    scatter_kernel<<<vecBlocks + scalarBlocks, 256, 0, stream>>>(
        obs, (const f4*)am_c, (const f4*)sd_c, cr_c, idx_t, e_t,
        (f4*)out, out + cr_off, out + idx_off, out + loss_off,
        B, 1.25f / ((float)B * 64.0f));
}